// Round 3
// baseline (4693.434 us; speedup 1.0000x reference)
//
#include <hip/hip_runtime.h>
#include <math.h>

typedef __bf16 bf16_t;
typedef __bf16 bf16x8 __attribute__((ext_vector_type(8)));
typedef float f32x4 __attribute__((ext_vector_type(4)));
typedef unsigned long long u64;

#define HID 2048
#define NBATCH 16
#define SEQLEN 512
#define MTOT (NBATCH * SEQLEN)
#define NBLK 64
#define RTHREADS 512
#define LN_EPS 1e-5f
#define FLAG_STRIDE 32   // 128B per flag line

// ================= GEMM: inp = x @ Wi^T + b  -> d_out (fp32) =================
__global__ __launch_bounds__(256) void gemm_proj(
    const float* __restrict__ X,
    const float* __restrict__ Wi,
    const float* __restrict__ bias,
    float* __restrict__ C,
    int* __restrict__ flags)
{
    __shared__ bf16_t lA[128 * 32];
    __shared__ bf16_t lB[128 * 32];
    const int tid = threadIdx.x;
    if (blockIdx.x == 0 && blockIdx.y == 0) {
        for (int i = tid; i < NBLK * FLAG_STRIDE; i += 256) flags[i] = 0;
    }
    const int lane = tid & 63;
    const int wv = tid >> 6;
    const int bn = blockIdx.x * 128;
    const int bm = blockIdx.y * 128;
    const int wr = (wv >> 1) * 64;
    const int wc = (wv & 1) * 64;

    f32x4 zero = {0.f, 0.f, 0.f, 0.f};
    f32x4 acc[4][4];
#pragma unroll
    for (int i = 0; i < 4; ++i)
#pragma unroll
        for (int j = 0; j < 4; ++j) acc[i][j] = zero;

    for (int k0 = 0; k0 < HID; k0 += 32) {
        __syncthreads();
#pragma unroll
        for (int c = 0; c < 2; ++c) {
            const int chunk = c * 256 + tid;      // 0..511
            const int row = chunk >> 2;           // 0..127
            const int kp = (chunk & 3) ^ (row & 3); // XOR-swizzled source chunk
            {
                const float* s = X + (size_t)(bm + row) * HID + k0 + kp * 8;
                float4 a0 = *(const float4*)s;
                float4 a1 = *(const float4*)(s + 4);
                bf16x8 v;
                v[0] = (bf16_t)a0.x; v[1] = (bf16_t)a0.y; v[2] = (bf16_t)a0.z; v[3] = (bf16_t)a0.w;
                v[4] = (bf16_t)a1.x; v[5] = (bf16_t)a1.y; v[6] = (bf16_t)a1.z; v[7] = (bf16_t)a1.w;
                *(bf16x8*)(lA + chunk * 8) = v;
            }
            {
                const float* s = Wi + (size_t)(bn + row) * HID + k0 + kp * 8;
                float4 a0 = *(const float4*)s;
                float4 a1 = *(const float4*)(s + 4);
                bf16x8 v;
                v[0] = (bf16_t)a0.x; v[1] = (bf16_t)a0.y; v[2] = (bf16_t)a0.z; v[3] = (bf16_t)a0.w;
                v[4] = (bf16_t)a1.x; v[5] = (bf16_t)a1.y; v[6] = (bf16_t)a1.z; v[7] = (bf16_t)a1.w;
                *(bf16x8*)(lB + chunk * 8) = v;
            }
        }
        __syncthreads();

        bf16x8 af[4], bfr[4];
#pragma unroll
        for (int i = 0; i < 4; ++i) {
            const int row = wr + i * 16 + (lane & 15);
            const int ck = (lane >> 4) ^ (row & 3);
            af[i] = *(const bf16x8*)(lA + row * 32 + ck * 8);
        }
#pragma unroll
        for (int j = 0; j < 4; ++j) {
            const int row = wc + j * 16 + (lane & 15);
            const int ck = (lane >> 4) ^ (row & 3);
            bfr[j] = *(const bf16x8*)(lB + row * 32 + ck * 8);
        }
#pragma unroll
        for (int i = 0; i < 4; ++i)
#pragma unroll
            for (int j = 0; j < 4; ++j)
                acc[i][j] = __builtin_amdgcn_mfma_f32_16x16x32_bf16(af[i], bfr[j], acc[i][j], 0, 0, 0);
    }

#pragma unroll
    for (int j = 0; j < 4; ++j) {
        const int col = bn + wc + j * 16 + (lane & 15);
        const float bv = bias[col];
#pragma unroll
        for (int i = 0; i < 4; ++i) {
#pragma unroll
            for (int r = 0; r < 4; ++r) {
                const int row = bm + wr + i * 16 + (lane >> 4) * 4 + r;
                C[(size_t)row * HID + col] = acc[i][j][r] + bv;
            }
        }
    }
}

// ================= Persistent recurrent kernel =================
// Coherence protocol (no bulk fences): all cross-block data (state ping-pong,
// flags) moves via relaxed AGENT-scope atomics (sc1 write-through stores /
// L2-bypassing loads). Ordering: state stores drain at the compiler-emitted
// s_waitcnt vmcnt(0) before s_barrier; the flag store issues after the
// barrier, so flag==t implies all of this block's step-(t-1) state is at the
// coherence point (L3). Readers' atomic loads fetch from L3, never stale L2.
__global__ __launch_bounds__(RTHREADS, 1) void recurrent(
    const float* __restrict__ Wr,
    const float* __restrict__ mask,
    const float* __restrict__ tau,
    float* __restrict__ io,      // d_out: holds inp (read rows t+1) -> states (write row t)
    bf16_t* __restrict__ st0,
    bf16_t* __restrict__ st1,
    int* __restrict__ flags)
{
    const int tid = threadIdx.x;
    const int lane = tid & 63;
    const int wv = tid >> 6;          // 0..7
    const int ct = wv >> 2;           // col-tile 0..1
    const int kq = wv & 3;            // K-quarter 0..3
    const int colbase = blockIdx.x * 32;

    __shared__ float red[2048];       // 8 waves x 256 partials

    // ---- preload masked recurrent weights as MFMA B-fragments (VGPR-resident) ----
    bf16x8 wf[16];
    {
        const int gc = colbase + ct * 16 + (lane & 15);
        const int kb = kq * 512 + (lane >> 4) * 8;
#pragma unroll
        for (int ks = 0; ks < 16; ++ks) {
            const size_t off = (size_t)gc * HID + kb + ks * 32;
            float4 a0 = *(const float4*)(Wr + off);
            float4 a1 = *(const float4*)(Wr + off + 4);
            float4 m0 = *(const float4*)(mask + off);
            float4 m1 = *(const float4*)(mask + off + 4);
            bf16x8 v;
            v[0] = (bf16_t)(a0.x * m0.x); v[1] = (bf16_t)(a0.y * m0.y);
            v[2] = (bf16_t)(a0.z * m0.z); v[3] = (bf16_t)(a0.w * m0.w);
            v[4] = (bf16_t)(a1.x * m1.x); v[5] = (bf16_t)(a1.y * m1.y);
            v[6] = (bf16_t)(a1.z * m1.z); v[7] = (bf16_t)(a1.w * m1.w);
            wf[ks] = v;
        }
    }

    // update-thread mapping: 512 threads <-> 16 batches x 32 cols
    const int ub = tid >> 5;
    const int uc = tid & 31;
    const int ugc = colbase + uc;
    float alpha;
    {
        float tv = tau[ugc];
        tv = fminf(fmaxf(tv, 1.0f), 20.0f);
        alpha = fminf(fmaxf(0.5f / tv, 0.0f), 1.0f);
    }

    float s_old = 0.f;
    float cur_inp = io[(size_t)ub * (SEQLEN * HID) + ugc];

    const int arow = lane & 15;                 // batch row of A fragment
    const int akb = kq * 512 + (lane >> 4) * 8; // k offset of A fragment
    const int rb = (uc >> 4) * 1024 + ub * 16 + (uc & 15);

    bf16_t* cur = st0;
    bf16_t* nxt = st1;

    // ---- step 0: state is zero -> rec = 0; no state read, no barrier needed ----
    {
        float z = fminf(fmaxf(cur_inp, -15.f), 15.f);
        const float e = __expf(2.0f * z);
        const float tgt = (e - 1.0f) / (e + 1.0f);
        float sn = alpha * tgt;                         // s_old == 0
        sn = fminf(fmaxf(sn, -1.0f), 1.0f);
        io[(size_t)ub * (SEQLEN * HID) + ugc] = sn;     // pre-LN output row 0
        // packed write-through state store (2 cols per uint32)
        float snp = __shfl_xor(sn, 1);
        if ((uc & 1) == 0) {
            union { bf16_t b[2]; unsigned int u; } p;
            p.b[0] = (bf16_t)sn;
            p.b[1] = (bf16_t)snp;
            __hip_atomic_store((unsigned int*)(nxt + (size_t)ub * HID + ugc), p.u,
                               __ATOMIC_RELAXED, __HIP_MEMORY_SCOPE_AGENT);
        }
        s_old = sn;
        cur_inp = io[(size_t)ub * (SEQLEN * HID) + HID + ugc];  // row 1 (still GEMM data)
        bf16_t* tmp = cur; cur = nxt; nxt = tmp;
    }

    for (int t = 1; t < SEQLEN; ++t) {
        // ---- lightweight grid sync: completed steps == t ----
        __syncthreads();   // compiler drains vmcnt -> this block's state stores at L3
        if (tid == 0)
            __hip_atomic_store(flags + (int)blockIdx.x * FLAG_STRIDE, t,
                               __ATOMIC_RELAXED, __HIP_MEMORY_SCOPE_AGENT);
        if (tid < 64) {
            int v;
            do {
                v = __hip_atomic_load(flags + tid * FLAG_STRIDE,
                                      __ATOMIC_RELAXED, __HIP_MEMORY_SCOPE_AGENT);
            } while (__ballot(v < t) != 0ull);
        }
        __syncthreads();

        // ---- coherent state fragment loads (bypass stale L2, hit L3) ----
        const u64* ab = (const u64*)(cur + (size_t)arow * HID + akb);
        bf16x8 af[16];
#pragma unroll
        for (int ks = 0; ks < 16; ++ks) {
            u64 lo = __hip_atomic_load(ab + ks * 8,     __ATOMIC_RELAXED, __HIP_MEMORY_SCOPE_AGENT);
            u64 hi = __hip_atomic_load(ab + ks * 8 + 1, __ATOMIC_RELAXED, __HIP_MEMORY_SCOPE_AGENT);
            union { u64 q[2]; bf16x8 v; } u;
            u.q[0] = lo; u.q[1] = hi;
            af[ks] = u.v;
        }

        // ---- matvec partial: 4 accumulators to shorten the dependent chain ----
        f32x4 a0 = {0.f,0.f,0.f,0.f}, a1v = {0.f,0.f,0.f,0.f};
        f32x4 a2 = {0.f,0.f,0.f,0.f}, a3 = {0.f,0.f,0.f,0.f};
#pragma unroll
        for (int ks = 0; ks < 16; ks += 4) {
            a0  = __builtin_amdgcn_mfma_f32_16x16x32_bf16(af[ks],     wf[ks],     a0,  0, 0, 0);
            a1v = __builtin_amdgcn_mfma_f32_16x16x32_bf16(af[ks + 1], wf[ks + 1], a1v, 0, 0, 0);
            a2  = __builtin_amdgcn_mfma_f32_16x16x32_bf16(af[ks + 2], wf[ks + 2], a2,  0, 0, 0);
            a3  = __builtin_amdgcn_mfma_f32_16x16x32_bf16(af[ks + 3], wf[ks + 3], a3,  0, 0, 0);
        }
        f32x4 acc = (a0 + a1v) + (a2 + a3);

        // ---- cross-wave K reduction via LDS ----
        const int wbase = wv * 256 + (lane >> 4) * 64 + (lane & 15);
        red[wbase]      = acc[0];
        red[wbase + 16] = acc[1];
        red[wbase + 32] = acc[2];
        red[wbase + 48] = acc[3];
        __syncthreads();
        const float rec = red[rb] + red[rb + 256] + red[rb + 512] + red[rb + 768];

        // prefetch next timestep's input (row t+1 of io; still GEMM data)
        const int tn = (t < SEQLEN - 1) ? (t + 1) : t;
        const float next_inp = io[(size_t)ub * (SEQLEN * HID) + (size_t)tn * HID + ugc];

        // ---- fused update: tanh + EMA + clip ----
        float z = cur_inp + rec;
        z = fminf(fmaxf(z, -15.f), 15.f);
        const float e = __expf(2.0f * z);
        const float tgt = (e - 1.0f) / (e + 1.0f);
        float sn = s_old + alpha * (tgt - s_old);
        sn = fminf(fmaxf(sn, -1.0f), 1.0f);

        io[(size_t)ub * (SEQLEN * HID) + (size_t)t * HID + ugc] = sn;   // pre-LN output

        // packed write-through state store
        float snp = __shfl_xor(sn, 1);
        if ((uc & 1) == 0) {
            union { bf16_t b[2]; unsigned int u; } p;
            p.b[0] = (bf16_t)sn;
            p.b[1] = (bf16_t)snp;
            __hip_atomic_store((unsigned int*)(nxt + (size_t)ub * HID + ugc), p.u,
                               __ATOMIC_RELAXED, __HIP_MEMORY_SCOPE_AGENT);
        }

        s_old = sn;
        cur_inp = next_inp;
        bf16_t* tmp = cur; cur = nxt; nxt = tmp;
    }
}

// ================= LayerNorm (in-place on d_out) =================
__global__ __launch_bounds__(256) void ln_kernel(
    float* __restrict__ io,
    const float* __restrict__ gamma,
    const float* __restrict__ beta)
{
    const size_t row = blockIdx.x;
    float* p = io + row * HID;
    const int tid = threadIdx.x;
    float4 v0 = *(const float4*)(p + tid * 4);
    float4 v1 = *(const float4*)(p + 1024 + tid * 4);
    float s  = v0.x + v0.y + v0.z + v0.w + v1.x + v1.y + v1.z + v1.w;
    float ss = v0.x * v0.x + v0.y * v0.y + v0.z * v0.z + v0.w * v0.w
             + v1.x * v1.x + v1.y * v1.y + v1.z * v1.z + v1.w * v1.w;
#pragma unroll
    for (int off = 32; off > 0; off >>= 1) {
        s  += __shfl_down(s, off, 64);
        ss += __shfl_down(ss, off, 64);
    }
    __shared__ float rs[4], rss[4];
    if ((tid & 63) == 0) { rs[tid >> 6] = s; rss[tid >> 6] = ss; }
    __syncthreads();
    s  = rs[0] + rs[1] + rs[2] + rs[3];
    ss = rss[0] + rss[1] + rss[2] + rss[3];
    const float mu = s * (1.f / HID);
    const float var = ss * (1.f / HID) - mu * mu;
    const float inv = rsqrtf(var + LN_EPS);
    const int c0 = tid * 4, c1 = 1024 + tid * 4;
    float4 g0 = *(const float4*)(gamma + c0);
    float4 g1 = *(const float4*)(gamma + c1);
    float4 b0 = *(const float4*)(beta + c0);
    float4 b1 = *(const float4*)(beta + c1);
    float4 o0, o1;
    o0.x = (v0.x - mu) * inv * g0.x + b0.x;
    o0.y = (v0.y - mu) * inv * g0.y + b0.y;
    o0.z = (v0.z - mu) * inv * g0.z + b0.z;
    o0.w = (v0.w - mu) * inv * g0.w + b0.w;
    o1.x = (v1.x - mu) * inv * g1.x + b1.x;
    o1.y = (v1.y - mu) * inv * g1.y + b1.y;
    o1.z = (v1.z - mu) * inv * g1.z + b1.z;
    o1.w = (v1.w - mu) * inv * g1.w + b1.w;
    *(float4*)(p + tid * 4) = o0;
    *(float4*)(p + 1024 + tid * 4) = o1;
}

extern "C" void kernel_launch(void* const* d_in, const int* in_sizes, int n_in,
                              void* d_out, int out_size, void* d_ws, size_t ws_size,
                              hipStream_t stream)
{
    const float* x     = (const float*)d_in[0];
    const float* Wi    = (const float*)d_in[1];
    const float* bias  = (const float*)d_in[2];
    const float* Wr    = (const float*)d_in[3];
    const float* mask  = (const float*)d_in[4];
    const float* tau   = (const float*)d_in[5];
    const float* gamma = (const float*)d_in[6];
    const float* beta  = (const float*)d_in[7];
    float* out = (float*)d_out;

    bf16_t* st0 = (bf16_t*)d_ws;
    bf16_t* st1 = st0 + (size_t)NBATCH * HID;
    int* flags  = (int*)(st1 + (size_t)NBATCH * HID);

    // 1) input projection -> d_out rows hold inp[b,t,:] (fp32); also zeroes flags
    gemm_proj<<<dim3(16, 64), 256, 0, stream>>>(x, Wi, bias, out, flags);
    // 2) persistent recurrence: overwrites d_out rows with pre-LN states
    recurrent<<<NBLK, RTHREADS, 0, stream>>>(Wr, mask, tau, out, st0, st1, flags);
    // 3) layernorm in-place
    ln_kernel<<<MTOT, 256, 0, stream>>>(out, gamma, beta);
}

// Round 4
// 2635.824 us; speedup vs baseline: 1.7806x; 1.7806x over previous
//
#include <hip/hip_runtime.h>
#include <math.h>

typedef __bf16 bf16_t;
typedef __bf16 bf16x8 __attribute__((ext_vector_type(8)));
typedef float f32x4 __attribute__((ext_vector_type(4)));
typedef int i32x4 __attribute__((ext_vector_type(4)));
typedef unsigned long long u64;

#define HID 2048
#define NBATCH 16
#define SEQLEN 512
#define MTOT (NBATCH * SEQLEN)
#define NBLK 64
#define RTHREADS 512
#define LN_EPS 1e-5f

// ================= GEMM: inp = x @ Wi^T + b  -> d_out (fp32) =================
__global__ __launch_bounds__(256) void gemm_proj(
    const float* __restrict__ X,
    const float* __restrict__ Wi,
    const float* __restrict__ bias,
    float* __restrict__ C,
    int* __restrict__ flags)
{
    __shared__ bf16_t lA[128 * 32];
    __shared__ bf16_t lB[128 * 32];
    const int tid = threadIdx.x;
    if (blockIdx.x == 0 && blockIdx.y == 0) {
        if (tid < NBLK) flags[tid] = 0;
    }
    const int lane = tid & 63;
    const int wv = tid >> 6;
    const int bn = blockIdx.x * 128;
    const int bm = blockIdx.y * 128;
    const int wr = (wv >> 1) * 64;
    const int wc = (wv & 1) * 64;

    f32x4 zero = {0.f, 0.f, 0.f, 0.f};
    f32x4 acc[4][4];
#pragma unroll
    for (int i = 0; i < 4; ++i)
#pragma unroll
        for (int j = 0; j < 4; ++j) acc[i][j] = zero;

    for (int k0 = 0; k0 < HID; k0 += 32) {
        __syncthreads();
#pragma unroll
        for (int c = 0; c < 2; ++c) {
            const int chunk = c * 256 + tid;      // 0..511
            const int row = chunk >> 2;           // 0..127
            const int kp = (chunk & 3) ^ (row & 3); // XOR-swizzled source chunk
            {
                const float* s = X + (size_t)(bm + row) * HID + k0 + kp * 8;
                float4 a0 = *(const float4*)s;
                float4 a1 = *(const float4*)(s + 4);
                bf16x8 v;
                v[0] = (bf16_t)a0.x; v[1] = (bf16_t)a0.y; v[2] = (bf16_t)a0.z; v[3] = (bf16_t)a0.w;
                v[4] = (bf16_t)a1.x; v[5] = (bf16_t)a1.y; v[6] = (bf16_t)a1.z; v[7] = (bf16_t)a1.w;
                *(bf16x8*)(lA + chunk * 8) = v;
            }
            {
                const float* s = Wi + (size_t)(bn + row) * HID + k0 + kp * 8;
                float4 a0 = *(const float4*)s;
                float4 a1 = *(const float4*)(s + 4);
                bf16x8 v;
                v[0] = (bf16_t)a0.x; v[1] = (bf16_t)a0.y; v[2] = (bf16_t)a0.z; v[3] = (bf16_t)a0.w;
                v[4] = (bf16_t)a1.x; v[5] = (bf16_t)a1.y; v[6] = (bf16_t)a1.z; v[7] = (bf16_t)a1.w;
                *(bf16x8*)(lB + chunk * 8) = v;
            }
        }
        __syncthreads();

        bf16x8 af[4], bfr[4];
#pragma unroll
        for (int i = 0; i < 4; ++i) {
            const int row = wr + i * 16 + (lane & 15);
            const int ck = (lane >> 4) ^ (row & 3);
            af[i] = *(const bf16x8*)(lA + row * 32 + ck * 8);
        }
#pragma unroll
        for (int j = 0; j < 4; ++j) {
            const int row = wc + j * 16 + (lane & 15);
            const int ck = (lane >> 4) ^ (row & 3);
            bfr[j] = *(const bf16x8*)(lB + row * 32 + ck * 8);
        }
#pragma unroll
        for (int i = 0; i < 4; ++i)
#pragma unroll
            for (int j = 0; j < 4; ++j)
                acc[i][j] = __builtin_amdgcn_mfma_f32_16x16x32_bf16(af[i], bfr[j], acc[i][j], 0, 0, 0);
    }

#pragma unroll
    for (int j = 0; j < 4; ++j) {
        const int col = bn + wc + j * 16 + (lane & 15);
        const float bv = bias[col];
#pragma unroll
        for (int i = 0; i < 4; ++i) {
#pragma unroll
            for (int r = 0; r < 4; ++r) {
                const int row = bm + wr + i * 16 + (lane >> 4) * 4 + r;
                C[(size_t)row * HID + col] = acc[i][j][r] + bv;
            }
        }
    }
}

// ================= Persistent recurrent kernel =================
// 64 blocks x 512 thr. Block owns 32 output cols. 8 waves = 8 K-eighths:
// wave kq reads state cols [kq*256, kq*256+256) = source blocks [kq*8, kq*8+8).
// Sync: 64 contiguous flag ints (1-2 cache lines). Producer publishes step t
// after the syncthreads that drains its step-(t-1) stores; wave kq waits only
// on its 8 source flags (union over the block's 8 waves covers all 64 blocks,
// and writes happen after the all-wave LDS barrier -> ping-pong stays safe).
// State loads: device-coherent global_load_dwordx4 sc0 sc1 (L1/L2 bypass).
__global__ __launch_bounds__(RTHREADS, 1) void recurrent(
    const float* __restrict__ Wr,
    const float* __restrict__ mask,
    const float* __restrict__ tau,
    float* __restrict__ io,      // d_out: holds inp (read rows t+1) -> states (write row t)
    bf16_t* __restrict__ st0,
    bf16_t* __restrict__ st1,
    int* __restrict__ flags)
{
    const int tid = threadIdx.x;
    const int lane = tid & 63;
    const int wv = tid >> 6;          // K-eighth 0..7
    const int colbase = blockIdx.x * 32;

    __shared__ float red[8 * 528];    // [kq][batch][col] stride-33 padded

    // ---- preload masked recurrent weights as MFMA B-fragments (VGPR-resident) ----
    // wave wv covers K rows [wv*256, wv*256+256) for BOTH 16-col tiles.
    bf16x8 wf0[8], wf1[8];
    {
        const int kb = wv * 256 + (lane >> 4) * 8;
#pragma unroll
        for (int ct = 0; ct < 2; ++ct) {
            const int gc = colbase + ct * 16 + (lane & 15);
#pragma unroll
            for (int ks = 0; ks < 8; ++ks) {
                const size_t off = (size_t)gc * HID + kb + ks * 32;
                float4 a0 = *(const float4*)(Wr + off);
                float4 a1 = *(const float4*)(Wr + off + 4);
                float4 m0 = *(const float4*)(mask + off);
                float4 m1 = *(const float4*)(mask + off + 4);
                bf16x8 v;
                v[0] = (bf16_t)(a0.x * m0.x); v[1] = (bf16_t)(a0.y * m0.y);
                v[2] = (bf16_t)(a0.z * m0.z); v[3] = (bf16_t)(a0.w * m0.w);
                v[4] = (bf16_t)(a1.x * m1.x); v[5] = (bf16_t)(a1.y * m1.y);
                v[6] = (bf16_t)(a1.z * m1.z); v[7] = (bf16_t)(a1.w * m1.w);
                if (ct == 0) wf0[ks] = v; else wf1[ks] = v;
            }
        }
    }

    // update-thread mapping: 512 threads <-> 16 batches x 32 cols
    const int ub = tid >> 5;
    const int uc = tid & 31;
    const int ugc = colbase + uc;
    float alpha;
    {
        float tv = tau[ugc];
        tv = fminf(fmaxf(tv, 1.0f), 20.0f);
        alpha = fminf(fmaxf(0.5f / tv, 0.0f), 1.0f);
    }

    float s_old = 0.f;
    float cur_inp = io[(size_t)ub * (SEQLEN * HID) + ugc];

    const int arow = lane & 15;                     // batch row of A fragment
    const int akb = wv * 256 + (lane >> 4) * 8;     // k offset of A fragment
    const int src = (wv << 3) + (lane & 7);         // this wave's 8 source flags

    bf16_t* cur = st0;
    bf16_t* nxt = st1;

    // ---- step 0: state is zero -> rec = 0; no state read, no publish ----
    {
        float z = fminf(fmaxf(cur_inp, -15.f), 15.f);
        const float e = __expf(2.0f * z);
        const float tgt = (e - 1.0f) / (e + 1.0f);
        float sn = alpha * tgt;                         // s_old == 0
        sn = fminf(fmaxf(sn, -1.0f), 1.0f);
        io[(size_t)ub * (SEQLEN * HID) + ugc] = sn;     // pre-LN output row 0
        float snp = __shfl_xor(sn, 1);
        if ((uc & 1) == 0) {
            union { bf16_t b[2]; unsigned int u; } p;
            p.b[0] = (bf16_t)sn;
            p.b[1] = (bf16_t)snp;
            __hip_atomic_store((unsigned int*)(nxt + (size_t)ub * HID + ugc), p.u,
                               __ATOMIC_RELAXED, __HIP_MEMORY_SCOPE_AGENT);
        }
        s_old = sn;
        cur_inp = io[(size_t)ub * (SEQLEN * HID) + HID + ugc];  // row 1 (still GEMM data)
        bf16_t* tmp = cur; cur = nxt; nxt = tmp;
    }

    for (int t = 1; t < SEQLEN; ++t) {
        // ---- A: join waves; drains vmcnt -> step-(t-1) state stores are at L3 ----
        __syncthreads();
        if (tid == 0)
            __hip_atomic_store(flags + (int)blockIdx.x, t,
                               __ATOMIC_RELAXED, __HIP_MEMORY_SCOPE_AGENT);
        // ---- per-wave subset wait: my 8 source blocks published step t ----
        {
            int v;
            do {
                v = __hip_atomic_load(flags + src, __ATOMIC_RELAXED, __HIP_MEMORY_SCOPE_AGENT);
            } while (__ballot(v < t) != 0ull);
        }
        __builtin_amdgcn_sched_barrier(0);

        // ---- device-coherent state fragment loads (16B, L1/L2 bypass) ----
        const bf16_t* abase = cur + (size_t)arow * HID + akb;
        i32x4 q0, q1, q2, q3, q4, q5, q6, q7;
        asm volatile("global_load_dwordx4 %0, %1, off sc0 sc1"            : "=v"(q0) : "v"(abase) : "memory");
        asm volatile("global_load_dwordx4 %0, %1, off offset:64 sc0 sc1"  : "=v"(q1) : "v"(abase) : "memory");
        asm volatile("global_load_dwordx4 %0, %1, off offset:128 sc0 sc1" : "=v"(q2) : "v"(abase) : "memory");
        asm volatile("global_load_dwordx4 %0, %1, off offset:192 sc0 sc1" : "=v"(q3) : "v"(abase) : "memory");
        asm volatile("global_load_dwordx4 %0, %1, off offset:256 sc0 sc1" : "=v"(q4) : "v"(abase) : "memory");
        asm volatile("global_load_dwordx4 %0, %1, off offset:320 sc0 sc1" : "=v"(q5) : "v"(abase) : "memory");
        asm volatile("global_load_dwordx4 %0, %1, off offset:384 sc0 sc1" : "=v"(q6) : "v"(abase) : "memory");
        asm volatile("global_load_dwordx4 %0, %1, off offset:448 sc0 sc1" : "=v"(q7) : "v"(abase) : "memory");
        asm volatile("s_waitcnt vmcnt(0)" ::: "memory");
        __builtin_amdgcn_sched_barrier(0);

        union { i32x4 i; bf16x8 v; } u0, u1, u2, u3, u4, u5, u6, u7;
        u0.i = q0; u1.i = q1; u2.i = q2; u3.i = q3;
        u4.i = q4; u5.i = q5; u6.i = q6; u7.i = q7;

        // ---- matvec partial: 4 independent MFMA chains of 4 ----
        f32x4 c0 = {0.f,0.f,0.f,0.f}, c1 = {0.f,0.f,0.f,0.f};
        f32x4 c2 = {0.f,0.f,0.f,0.f}, c3 = {0.f,0.f,0.f,0.f};
        c0 = __builtin_amdgcn_mfma_f32_16x16x32_bf16(u0.v, wf0[0], c0, 0, 0, 0);
        c1 = __builtin_amdgcn_mfma_f32_16x16x32_bf16(u1.v, wf0[1], c1, 0, 0, 0);
        c2 = __builtin_amdgcn_mfma_f32_16x16x32_bf16(u0.v, wf1[0], c2, 0, 0, 0);
        c3 = __builtin_amdgcn_mfma_f32_16x16x32_bf16(u1.v, wf1[1], c3, 0, 0, 0);
        c0 = __builtin_amdgcn_mfma_f32_16x16x32_bf16(u2.v, wf0[2], c0, 0, 0, 0);
        c1 = __builtin_amdgcn_mfma_f32_16x16x32_bf16(u3.v, wf0[3], c1, 0, 0, 0);
        c2 = __builtin_amdgcn_mfma_f32_16x16x32_bf16(u2.v, wf1[2], c2, 0, 0, 0);
        c3 = __builtin_amdgcn_mfma_f32_16x16x32_bf16(u3.v, wf1[3], c3, 0, 0, 0);
        c0 = __builtin_amdgcn_mfma_f32_16x16x32_bf16(u4.v, wf0[4], c0, 0, 0, 0);
        c1 = __builtin_amdgcn_mfma_f32_16x16x32_bf16(u5.v, wf0[5], c1, 0, 0, 0);
        c2 = __builtin_amdgcn_mfma_f32_16x16x32_bf16(u4.v, wf1[4], c2, 0, 0, 0);
        c3 = __builtin_amdgcn_mfma_f32_16x16x32_bf16(u5.v, wf1[5], c3, 0, 0, 0);
        c0 = __builtin_amdgcn_mfma_f32_16x16x32_bf16(u6.v, wf0[6], c0, 0, 0, 0);
        c1 = __builtin_amdgcn_mfma_f32_16x16x32_bf16(u7.v, wf0[7], c1, 0, 0, 0);
        c2 = __builtin_amdgcn_mfma_f32_16x16x32_bf16(u6.v, wf1[6], c2, 0, 0, 0);
        c3 = __builtin_amdgcn_mfma_f32_16x16x32_bf16(u7.v, wf1[7], c3, 0, 0, 0);
        f32x4 accA = c0 + c1;   // ct=0 partial (16 cols)
        f32x4 accB = c2 + c3;   // ct=1 partial

        // ---- cross-wave K reduction via LDS (stride-33 pad) ----
        {
            const int colA = lane & 15;
            const int colB = 16 + (lane & 15);
            const int r0 = (lane >> 4) * 4;
            const int base = wv * 528;
#pragma unroll
            for (int r = 0; r < 4; ++r) {
                red[base + (r0 + r) * 33 + colA] = accA[r];
                red[base + (r0 + r) * 33 + colB] = accB[r];
            }
        }
        __syncthreads();   // B
        float rec = 0.f;
#pragma unroll
        for (int q = 0; q < 8; ++q)
            rec += red[q * 528 + ub * 33 + uc];

        // prefetch next timestep's input (row t+1 of io; still GEMM data)
        const int tn = (t < SEQLEN - 1) ? (t + 1) : t;
        const float next_inp = io[(size_t)ub * (SEQLEN * HID) + (size_t)tn * HID + ugc];

        // ---- fused update: tanh + EMA + clip ----
        float z = cur_inp + rec;
        z = fminf(fmaxf(z, -15.f), 15.f);
        const float e = __expf(2.0f * z);
        const float tgt = (e - 1.0f) / (e + 1.0f);
        float sn = s_old + alpha * (tgt - s_old);
        sn = fminf(fmaxf(sn, -1.0f), 1.0f);

        io[(size_t)ub * (SEQLEN * HID) + (size_t)t * HID + ugc] = sn;   // pre-LN output

        // packed write-through state store (2 cols per uint32)
        float snp = __shfl_xor(sn, 1);
        if ((uc & 1) == 0) {
            union { bf16_t b[2]; unsigned int u; } p;
            p.b[0] = (bf16_t)sn;
            p.b[1] = (bf16_t)snp;
            __hip_atomic_store((unsigned int*)(nxt + (size_t)ub * HID + ugc), p.u,
                               __ATOMIC_RELAXED, __HIP_MEMORY_SCOPE_AGENT);
        }

        s_old = sn;
        cur_inp = next_inp;
        bf16_t* tmp = cur; cur = nxt; nxt = tmp;
    }
}

// ================= LayerNorm (in-place on d_out) =================
__global__ __launch_bounds__(256) void ln_kernel(
    float* __restrict__ io,
    const float* __restrict__ gamma,
    const float* __restrict__ beta)
{
    const size_t row = blockIdx.x;
    float* p = io + row * HID;
    const int tid = threadIdx.x;
    float4 v0 = *(const float4*)(p + tid * 4);
    float4 v1 = *(const float4*)(p + 1024 + tid * 4);
    float s  = v0.x + v0.y + v0.z + v0.w + v1.x + v1.y + v1.z + v1.w;
    float ss = v0.x * v0.x + v0.y * v0.y + v0.z * v0.z + v0.w * v0.w
             + v1.x * v1.x + v1.y * v1.y + v1.z * v1.z + v1.w * v1.w;
#pragma unroll
    for (int off = 32; off > 0; off >>= 1) {
        s  += __shfl_down(s, off, 64);
        ss += __shfl_down(ss, off, 64);
    }
    __shared__ float rs[4], rss[4];
    if ((tid & 63) == 0) { rs[tid >> 6] = s; rss[tid >> 6] = ss; }
    __syncthreads();
    s  = rs[0] + rs[1] + rs[2] + rs[3];
    ss = rss[0] + rss[1] + rss[2] + rss[3];
    const float mu = s * (1.f / HID);
    const float var = ss * (1.f / HID) - mu * mu;
    const float inv = rsqrtf(var + LN_EPS);
    const int c0 = tid * 4, c1 = 1024 + tid * 4;
    float4 g0 = *(const float4*)(gamma + c0);
    float4 g1 = *(const float4*)(gamma + c1);
    float4 b0 = *(const float4*)(beta + c0);
    float4 b1 = *(const float4*)(beta + c1);
    float4 o0, o1;
    o0.x = (v0.x - mu) * inv * g0.x + b0.x;
    o0.y = (v0.y - mu) * inv * g0.y + b0.y;
    o0.z = (v0.z - mu) * inv * g0.z + b0.z;
    o0.w = (v0.w - mu) * inv * g0.w + b0.w;
    o1.x = (v1.x - mu) * inv * g1.x + b1.x;
    o1.y = (v1.y - mu) * inv * g1.y + b1.y;
    o1.z = (v1.z - mu) * inv * g1.z + b1.z;
    o1.w = (v1.w - mu) * inv * g1.w + b1.w;
    *(float4*)(p + tid * 4) = o0;
    *(float4*)(p + 1024 + tid * 4) = o1;
}

extern "C" void kernel_launch(void* const* d_in, const int* in_sizes, int n_in,
                              void* d_out, int out_size, void* d_ws, size_t ws_size,
                              hipStream_t stream)
{
    const float* x     = (const float*)d_in[0];
    const float* Wi    = (const float*)d_in[1];
    const float* bias  = (const float*)d_in[2];
    const float* Wr    = (const float*)d_in[3];
    const float* mask  = (const float*)d_in[4];
    const float* tau   = (const float*)d_in[5];
    const float* gamma = (const float*)d_in[6];
    const float* beta  = (const float*)d_in[7];
    float* out = (float*)d_out;

    bf16_t* st0 = (bf16_t*)d_ws;
    bf16_t* st1 = st0 + (size_t)NBATCH * HID;
    int* flags  = (int*)(st1 + (size_t)NBATCH * HID);

    // 1) input projection -> d_out rows hold inp[b,t,:] (fp32); also zeroes flags
    gemm_proj<<<dim3(16, 64), 256, 0, stream>>>(x, Wi, bias, out, flags);
    // 2) persistent recurrence: overwrites d_out rows with pre-LN states
    recurrent<<<NBLK, RTHREADS, 0, stream>>>(Wr, mask, tau, out, st0, st1, flags);
    // 3) layernorm in-place
    ln_kernel<<<MTOT, 256, 0, stream>>>(out, gamma, beta);
}